// Round 1
// baseline (2758.962 us; speedup 1.0000x reference)
//
#include <hip/hip_runtime.h>
#include <hip/hip_bf16.h>

#define T_TOKENS 65536
#define D_DIM 256
#define H_DIM 1024
#define E_NUM 8
#define MT 64
#define HC 64

typedef __attribute__((ext_vector_type(4))) float f32x4;
typedef __attribute__((ext_vector_type(8))) short s16x8;

__device__ __forceinline__ unsigned short f2bf(float f){
  union { float f; unsigned u; } v; v.f = f;
  unsigned r = v.u + 0x7FFFu + ((v.u >> 16) & 1u);
  return (unsigned short)(r >> 16);
}

// ---- convert W1/W2 to bf16 (8.4 MB total -> L2-resident) ----
__global__ __launch_bounds__(256) void cvt_w(const float* __restrict__ W1,
                                             const float* __restrict__ W2,
                                             unsigned short* __restrict__ w1b,
                                             unsigned short* __restrict__ w2b){
  int i = blockIdx.x * 256 + threadIdx.x;          // unit of 4 floats
  const int N1 = (E_NUM * H_DIM * D_DIM) / 4;      // 524288
  const float* src; unsigned short* dst; int j;
  if (i < N1){ src = W1; dst = w1b; j = i; }
  else       { src = W2; dst = w2b; j = i - N1; }
  f32x4 v = ((const f32x4*)src)[j];
  unsigned long long pk = (unsigned long long)f2bf(v.x)
                        | ((unsigned long long)f2bf(v.y) << 16)
                        | ((unsigned long long)f2bf(v.z) << 32)
                        | ((unsigned long long)f2bf(v.w) << 48);
  *(unsigned long long*)(dst + 4*(size_t)j) = pk;
}

// ---- gate: scores, top-2, softmax, scatter routing, out := p0*b2[e0]+p1*b2[e1] ----
__global__ __launch_bounds__(256) void gate_kernel(
    const float* __restrict__ x, const float* __restrict__ Wg,
    const float* __restrict__ bg, const float* __restrict__ b2,
    int* __restrict__ counts, int* __restrict__ tok_ids, float* __restrict__ tok_p,
    float* __restrict__ out)
{
  int wave = threadIdx.x >> 6, lane = threadIdx.x & 63;
  int t = blockIdx.x * 4 + wave;
  f32x4 xv = *(const f32x4*)(x + (size_t)t * D_DIM + 4*lane);
  float s[E_NUM];
#pragma unroll
  for (int e = 0; e < E_NUM; ++e){
    f32x4 w = *(const f32x4*)(Wg + e*D_DIM + 4*lane);
    s[e] = xv.x*w.x + xv.y*w.y + xv.z*w.z + xv.w*w.w;
  }
#pragma unroll
  for (int off = 32; off; off >>= 1){
#pragma unroll
    for (int e = 0; e < E_NUM; ++e) s[e] += __shfl_xor(s[e], off);
  }
#pragma unroll
  for (int e = 0; e < E_NUM; ++e) s[e] += bg[e];
  // top-2, ties -> lower index (strict >)
  int e0 = 0; float v0 = s[0];
#pragma unroll
  for (int e = 1; e < E_NUM; ++e) if (s[e] > v0){ v0 = s[e]; e0 = e; }
  int e1 = -1; float v1 = -3.4e38f;
#pragma unroll
  for (int e = 0; e < E_NUM; ++e){
    if (e == e0) continue;
    if (s[e] > v1){ v1 = s[e]; e1 = e; }
  }
  float ex = __expf(v1 - v0);
  float inv = 1.f / (1.f + ex);
  float p0 = inv, p1 = ex * inv;
  if (lane == 0){
    int pos0 = atomicAdd(counts + e0, 1);
    tok_ids[e0*T_TOKENS + pos0] = t; tok_p[e0*T_TOKENS + pos0] = p0;
    int pos1 = atomicAdd(counts + e1, 1);
    tok_ids[e1*T_TOKENS + pos1] = t; tok_p[e1*T_TOKENS + pos1] = p1;
  }
  // init out with the combined b2 term (serves as the zero-init too)
  f32x4 bz0 = *(const f32x4*)(b2 + e0*D_DIM + 4*lane);
  f32x4 bz1 = *(const f32x4*)(b2 + e1*D_DIM + 4*lane);
  f32x4 o;
  o.x = p0*bz0.x + p1*bz1.x;
  o.y = p0*bz0.y + p1*bz1.y;
  o.z = p0*bz0.z + p1*bz1.z;
  o.w = p0*bz0.w + p1*bz1.w;
  *(f32x4*)(out + (size_t)t * D_DIM + 4*lane) = o;
}

// ---- grouped FFN: per expert, per 64-token tile, fused (x@W1^T,relu)@W2^T ----
__global__ __launch_bounds__(256) void ffn_kernel(
  const float* __restrict__ x,
  const unsigned short* __restrict__ w1b, const unsigned short* __restrict__ w2b,
  const float* __restrict__ b1,
  const int* __restrict__ counts, const int* __restrict__ tok_ids,
  const float* __restrict__ tok_p,
  float* __restrict__ out)
{
  int e = blockIdx.y;
  int cnt = counts[e];
  int base = blockIdx.x * MT;
  if (base >= cnt) return;

  __shared__ unsigned short Xs[MT * D_DIM];   // 32 KB, XOR-swizzled rows (512 B)
  __shared__ unsigned short Hs[MT * HC];      // 8 KB, XOR-swizzled rows (128 B)
  __shared__ int   sTok[MT];
  __shared__ float sP[MT];

  int tid = threadIdx.x, wave = tid >> 6, lane = tid & 63;

  if (tid < MT){
    int idx = base + tid;
    int tk = (idx < cnt) ? tok_ids[e*T_TOKENS + idx] : -1;
    sTok[tid] = tk;
    sP[tid]   = (idx < cnt) ? tok_p[e*T_TOKENS + idx] : 0.f;
  }
  __syncthreads();

  // gather + fp32->bf16 into swizzled Xs
  for (int u = tid; u < MT * (D_DIM/8); u += 256){
    int r = u >> 5;          // 32 16B-units per row
    int c = u & 31;
    int tk = sTok[r];
    s16x8 v = (s16x8)(short)0;
    if (tk >= 0){
      const float* src = x + (size_t)tk * D_DIM + c*8;
      f32x4 a = *(const f32x4*)src;
      f32x4 b = *(const f32x4*)(src + 4);
      v[0]=(short)f2bf(a.x); v[1]=(short)f2bf(a.y); v[2]=(short)f2bf(a.z); v[3]=(short)f2bf(a.w);
      v[4]=(short)f2bf(b.x); v[5]=(short)f2bf(b.y); v[6]=(short)f2bf(b.z); v[7]=(short)f2bf(b.w);
    }
    int boff = (r*512 + c*16) ^ ((r & 7) << 4);
    *(s16x8*)((char*)Xs + boff) = v;
  }
  __syncthreads();

  f32x4 yacc[16];
#pragma unroll
  for (int n = 0; n < 16; ++n) yacc[n] = (f32x4){0.f,0.f,0.f,0.f};

  const int mrow = lane & 15;
  const int kq   = (lane >> 4) * 8;
  const size_t w1base = (size_t)e * H_DIM * D_DIM;
  const size_t w2base = (size_t)e * D_DIM * H_DIM;

  for (int hc = 0; hc < H_DIM; hc += HC){
    // ---- layer 1: h(64 x 64) = Xs(64 x 256) @ W1chunk^T ----
    f32x4 hacc[4];
#pragma unroll
    for (int n = 0; n < 4; ++n) hacc[n] = (f32x4){0.f,0.f,0.f,0.f};
#pragma unroll
    for (int k0 = 0; k0 < D_DIM; k0 += 32){
      int r = wave*16 + mrow;
      int aoff = (r*512 + (k0 + kq)*2) ^ ((r & 7) << 4);
      s16x8 afr = *(const s16x8*)((const char*)Xs + aoff);
#pragma unroll
      for (int n = 0; n < 4; ++n){
        int hrow = hc + n*16 + mrow;
        s16x8 bfr = *(const s16x8*)(w1b + w1base + (size_t)hrow*D_DIM + k0 + kq);
        hacc[n] = __builtin_amdgcn_mfma_f32_16x16x32_bf16(afr, bfr, hacc[n], 0, 0, 0);
      }
    }
    // bias + relu + bf16 -> Hs (each wave owns its own 16-row strip; no barrier needed)
#pragma unroll
    for (int n = 0; n < 4; ++n){
      int hh = hc + n*16 + mrow;
      float bias = b1[e*H_DIM + hh];
#pragma unroll
      for (int j = 0; j < 4; ++j){
        int m = wave*16 + (lane >> 4)*4 + j;
        float v = fmaxf(hacc[n][j] + bias, 0.f);
        int boff = (m*128 + (n*16 + mrow)*2) ^ ((m & 7) << 4);
        *(unsigned short*)((char*)Hs + boff) = f2bf(v);
      }
    }
    // ---- layer 2: y(64 x 256) += h(64 x 64) @ W2chunk^T ----
#pragma unroll
    for (int k0 = 0; k0 < HC; k0 += 32){
      int r = wave*16 + mrow;
      int aoff = (r*128 + (k0 + kq)*2) ^ ((r & 7) << 4);
      s16x8 afr = *(const s16x8*)((const char*)Hs + aoff);
#pragma unroll
      for (int n = 0; n < 16; ++n){
        int dcol = n*16 + mrow;
        s16x8 bfr = *(const s16x8*)(w2b + w2base + (size_t)dcol*H_DIM + hc + k0 + kq);
        yacc[n] = __builtin_amdgcn_mfma_f32_16x16x32_bf16(afr, bfr, yacc[n], 0, 0, 0);
      }
    }
  }

  // ---- scatter: out[tok] += p * y ----
#pragma unroll
  for (int j = 0; j < 4; ++j){
    int m = wave*16 + (lane >> 4)*4 + j;
    int tk = sTok[m];
    if (tk < 0) continue;
    float p = sP[m];
#pragma unroll
    for (int n = 0; n < 16; ++n){
      atomicAdd(out + (size_t)tk * D_DIM + n*16 + mrow, p * yacc[n][j]);
    }
  }
}

extern "C" void kernel_launch(void* const* d_in, const int* in_sizes, int n_in,
                              void* d_out, int out_size, void* d_ws, size_t ws_size,
                              hipStream_t stream) {
  const float* x  = (const float*)d_in[0];
  const float* Wg = (const float*)d_in[1];
  const float* bg = (const float*)d_in[2];
  const float* W1 = (const float*)d_in[3];
  const float* b1 = (const float*)d_in[4];
  const float* W2 = (const float*)d_in[5];
  const float* b2 = (const float*)d_in[6];
  float* out = (float*)d_out;
  char* ws = (char*)d_ws;

  unsigned short* w1b   = (unsigned short*)(ws);             // 4,194,304 B
  unsigned short* w2b   = (unsigned short*)(ws + 4194304);   // 4,194,304 B
  int*   counts  = (int*)  (ws + 8388608);                   // 64 B
  int*   tok_ids = (int*)  (ws + 8388672);                   // 2,097,152 B
  float* tok_p   = (float*)(ws + 10485824);                  // 2,097,152 B
  // total ws use: 12,582,976 B

  hipMemsetAsync(counts, 0, 64, stream);
  cvt_w<<<4096, 256, 0, stream>>>(W1, W2, w1b, w2b);
  gate_kernel<<<T_TOKENS/4, 256, 0, stream>>>(x, Wg, bg, b2, counts, tok_ids, tok_p, out);
  ffn_kernel<<<dim3(T_TOKENS/MT, E_NUM), 256, 0, stream>>>(x, w1b, w2b, b1,
                                                           counts, tok_ids, tok_p, out);
}

// Round 2
// 878.258 us; speedup vs baseline: 3.1414x; 3.1414x over previous
//
#include <hip/hip_runtime.h>
#include <hip/hip_bf16.h>

#define T_TOKENS 65536
#define D_DIM 256
#define H_DIM 1024
#define E_NUM 8
#define MT 64
#define HC 64
#define GTB 64   // gate tokens per block

typedef __attribute__((ext_vector_type(4))) float f32x4;
typedef __attribute__((ext_vector_type(8))) short s16x8;

__device__ __forceinline__ unsigned short f2bf(float f){
  union { float f; unsigned u; } v; v.f = f;
  unsigned r = v.u + 0x7FFFu + ((v.u >> 16) & 1u);
  return (unsigned short)(r >> 16);
}

// ---- convert W1/W2 to bf16 (8.4 MB total -> L2-resident) ----
__global__ __launch_bounds__(256) void cvt_w(const float* __restrict__ W1,
                                             const float* __restrict__ W2,
                                             unsigned short* __restrict__ w1b,
                                             unsigned short* __restrict__ w2b){
  int i = blockIdx.x * 256 + threadIdx.x;          // unit of 4 floats
  const int N1 = (E_NUM * H_DIM * D_DIM) / 4;      // 524288
  const float* src; unsigned short* dst; int j;
  if (i < N1){ src = W1; dst = w1b; j = i; }
  else       { src = W2; dst = w2b; j = i - N1; }
  f32x4 v = ((const f32x4*)src)[j];
  unsigned long long pk = (unsigned long long)f2bf(v.x)
                        | ((unsigned long long)f2bf(v.y) << 16)
                        | ((unsigned long long)f2bf(v.z) << 32)
                        | ((unsigned long long)f2bf(v.w) << 48);
  *(unsigned long long*)(dst + 4*(size_t)j) = pk;
}

// ---- gate: scores, top-2, softmax, hierarchical-atomic routing,
//      out := p0*b2[e0]+p1*b2[e1] (doubles as out init) ----
__global__ __launch_bounds__(256) void gate_kernel(
    const float* __restrict__ x, const float* __restrict__ Wg,
    const float* __restrict__ bg, const float* __restrict__ b2,
    int* __restrict__ counts, int* __restrict__ tok_ids, float* __restrict__ tok_p,
    float* __restrict__ out)
{
  __shared__ int lcnt[E_NUM];
  __shared__ int lbase[E_NUM];
  __shared__ unsigned char aexp[GTB * 2];
  __shared__ short         apos[GTB * 2];
  __shared__ float         aprb[GTB * 2];

  int tid = threadIdx.x, wave = tid >> 6, lane = tid & 63;
  if (tid < E_NUM) lcnt[tid] = 0;
  __syncthreads();

  int t0 = blockIdx.x * GTB;
#pragma unroll 1
  for (int i = 0; i < GTB / 4; ++i){
    int tl = wave * (GTB / 4) + i;          // local token index 0..63
    int t = t0 + tl;
    f32x4 xv = *(const f32x4*)(x + (size_t)t * D_DIM + 4*lane);
    float s[E_NUM];
#pragma unroll
    for (int e = 0; e < E_NUM; ++e){
      f32x4 w = *(const f32x4*)(Wg + e*D_DIM + 4*lane);
      s[e] = xv.x*w.x + xv.y*w.y + xv.z*w.z + xv.w*w.w;
    }
#pragma unroll
    for (int off = 32; off; off >>= 1){
#pragma unroll
      for (int e = 0; e < E_NUM; ++e) s[e] += __shfl_xor(s[e], off);
    }
#pragma unroll
    for (int e = 0; e < E_NUM; ++e) s[e] += bg[e];
    // top-2, ties -> lower index (strict >)
    int e0 = 0; float v0 = s[0];
#pragma unroll
    for (int e = 1; e < E_NUM; ++e) if (s[e] > v0){ v0 = s[e]; e0 = e; }
    int e1 = -1; float v1 = -3.4e38f;
#pragma unroll
    for (int e = 0; e < E_NUM; ++e){
      if (e == e0) continue;
      if (s[e] > v1){ v1 = s[e]; e1 = e; }
    }
    float ex = __expf(v1 - v0);
    float inv = 1.f / (1.f + ex);
    float p0 = inv, p1 = ex * inv;
    if (lane == 0){
      int li = tl * 2;
      int pos0 = atomicAdd(&lcnt[e0], 1);
      int pos1 = atomicAdd(&lcnt[e1], 1);
      aexp[li]   = (unsigned char)e0; apos[li]   = (short)pos0; aprb[li]   = p0;
      aexp[li+1] = (unsigned char)e1; apos[li+1] = (short)pos1; aprb[li+1] = p1;
    }
    // init out with the combined b2 term (serves as the zero-init too)
    f32x4 bz0 = *(const f32x4*)(b2 + e0*D_DIM + 4*lane);
    f32x4 bz1 = *(const f32x4*)(b2 + e1*D_DIM + 4*lane);
    f32x4 o;
    o.x = p0*bz0.x + p1*bz1.x;
    o.y = p0*bz0.y + p1*bz1.y;
    o.z = p0*bz0.z + p1*bz1.z;
    o.w = p0*bz0.w + p1*bz1.w;
    *(f32x4*)(out + (size_t)t * D_DIM + 4*lane) = o;
  }
  __syncthreads();
  if (tid < E_NUM) lbase[tid] = atomicAdd(counts + tid*16, lcnt[tid]);
  __syncthreads();
  if (tid < GTB * 2){
    int t = t0 + (tid >> 1);
    int e = aexp[tid];
    int idx = lbase[e] + apos[tid];
    tok_ids[e*T_TOKENS + idx] = t;
    tok_p  [e*T_TOKENS + idx] = aprb[tid];
  }
}

// ---- grouped FFN: per expert, per 64-token tile, 2 waves x 32 rows each,
//      fused (x@W1^T, relu) @ W2^T with 2x B-fragment reuse ----
__global__ __launch_bounds__(128, 2) void ffn_kernel(
  const float* __restrict__ x,
  const unsigned short* __restrict__ w1b, const unsigned short* __restrict__ w2b,
  const float* __restrict__ b1,
  const int* __restrict__ counts, const int* __restrict__ tok_ids,
  const float* __restrict__ tok_p,
  float* __restrict__ out)
{
  int e = blockIdx.y;
  int cnt = counts[e*16];
  int base = blockIdx.x * MT;
  if (base >= cnt) return;

  __shared__ unsigned short Xs[MT * D_DIM];   // 32 KB, XOR-swizzled rows (512 B)
  __shared__ unsigned short Hs[MT * HC];      // 8 KB, XOR-swizzled rows (128 B)
  __shared__ int   sTok[MT];
  __shared__ float sP[MT];

  int tid = threadIdx.x, wave = tid >> 6, lane = tid & 63;

  if (tid < MT){
    int idx = base + tid;
    int tk = (idx < cnt) ? tok_ids[e*T_TOKENS + idx] : -1;
    sTok[tid] = tk;
    sP[tid]   = (idx < cnt) ? tok_p[e*T_TOKENS + idx] : 0.f;
  }
  __syncthreads();

  // gather + fp32->bf16 into swizzled Xs (2048 16B-units, 128 threads)
  for (int u = tid; u < MT * (D_DIM/8); u += 128){
    int r = u >> 5;          // 32 16B-units per row
    int c = u & 31;
    int tk = sTok[r];
    s16x8 v = (s16x8)(short)0;
    if (tk >= 0){
      const float* src = x + (size_t)tk * D_DIM + c*8;
      f32x4 a = *(const f32x4*)src;
      f32x4 b = *(const f32x4*)(src + 4);
      v[0]=(short)f2bf(a.x); v[1]=(short)f2bf(a.y); v[2]=(short)f2bf(a.z); v[3]=(short)f2bf(a.w);
      v[4]=(short)f2bf(b.x); v[5]=(short)f2bf(b.y); v[6]=(short)f2bf(b.z); v[7]=(short)f2bf(b.w);
    }
    int boff = (r*512 + c*16) ^ ((r & 7) << 4);
    *(s16x8*)((char*)Xs + boff) = v;
  }
  __syncthreads();

  f32x4 yacc[2][16];
#pragma unroll
  for (int rb = 0; rb < 2; ++rb)
#pragma unroll
    for (int n = 0; n < 16; ++n) yacc[rb][n] = (f32x4){0.f,0.f,0.f,0.f};

  const int mrow = lane & 15;
  const int kq   = (lane >> 4) * 8;
  const int r0 = wave*32 + mrow;    // row-block 0
  const int r1 = r0 + 16;           // row-block 1
  const size_t w1base = (size_t)e * H_DIM * D_DIM;
  const size_t w2base = (size_t)e * D_DIM * H_DIM;

  for (int hc = 0; hc < H_DIM; hc += HC){
    // ---- layer 1: h(64 x 64) = Xs(64 x 256) @ W1chunk^T ----
    f32x4 hacc[2][4];
#pragma unroll
    for (int rb = 0; rb < 2; ++rb)
#pragma unroll
      for (int n = 0; n < 4; ++n) hacc[rb][n] = (f32x4){0.f,0.f,0.f,0.f};

    const unsigned short* w1p = w1b + w1base + (size_t)(hc + mrow)*D_DIM + kq;
#pragma unroll
    for (int k0 = 0; k0 < D_DIM; k0 += 32){
      int a0off = (r0*512 + (k0 + kq)*2) ^ ((r0 & 7) << 4);
      int a1off = (r1*512 + (k0 + kq)*2) ^ ((r1 & 7) << 4);
      s16x8 a0 = *(const s16x8*)((const char*)Xs + a0off);
      s16x8 a1 = *(const s16x8*)((const char*)Xs + a1off);
#pragma unroll
      for (int n = 0; n < 4; ++n){
        s16x8 bfr = *(const s16x8*)(w1p + n*16*D_DIM + k0);
        hacc[0][n] = __builtin_amdgcn_mfma_f32_16x16x32_bf16(a0, bfr, hacc[0][n], 0, 0, 0);
        hacc[1][n] = __builtin_amdgcn_mfma_f32_16x16x32_bf16(a1, bfr, hacc[1][n], 0, 0, 0);
      }
    }
    // bias + relu + bf16 -> Hs (each wave owns its own 32-row strip; no barrier)
#pragma unroll
    for (int rb = 0; rb < 2; ++rb){
#pragma unroll
      for (int n = 0; n < 4; ++n){
        int hh = hc + n*16 + mrow;
        float bias = b1[e*H_DIM + hh];
#pragma unroll
        for (int j = 0; j < 4; ++j){
          int m = wave*32 + rb*16 + (lane >> 4)*4 + j;
          float v = fmaxf(hacc[rb][n][j] + bias, 0.f);
          int boff = (m*128 + (n*16 + mrow)*2) ^ ((m & 7) << 4);
          *(unsigned short*)((char*)Hs + boff) = f2bf(v);
        }
      }
    }
    // ---- layer 2: y(64 x 256) += h(64 x 64) @ W2chunk^T ----
    const unsigned short* w2p = w2b + w2base + (size_t)mrow*H_DIM + hc + kq;
#pragma unroll
    for (int k0 = 0; k0 < HC; k0 += 32){
      int a0off = (r0*128 + (k0 + kq)*2) ^ ((r0 & 7) << 4);
      int a1off = (r1*128 + (k0 + kq)*2) ^ ((r1 & 7) << 4);
      s16x8 a0 = *(const s16x8*)((const char*)Hs + a0off);
      s16x8 a1 = *(const s16x8*)((const char*)Hs + a1off);
#pragma unroll
      for (int n = 0; n < 16; ++n){
        s16x8 bfr = *(const s16x8*)(w2p + n*16*H_DIM + k0);
        yacc[0][n] = __builtin_amdgcn_mfma_f32_16x16x32_bf16(a0, bfr, yacc[0][n], 0, 0, 0);
        yacc[1][n] = __builtin_amdgcn_mfma_f32_16x16x32_bf16(a1, bfr, yacc[1][n], 0, 0, 0);
      }
    }
  }

  // ---- scatter: out[tok] += p * y ----
#pragma unroll
  for (int rb = 0; rb < 2; ++rb){
#pragma unroll
    for (int j = 0; j < 4; ++j){
      int m = wave*32 + rb*16 + (lane >> 4)*4 + j;
      int tk = sTok[m];
      if (tk < 0) continue;
      float p = sP[m];
#pragma unroll
      for (int n = 0; n < 16; ++n){
        atomicAdd(out + (size_t)tk * D_DIM + n*16 + mrow, p * yacc[rb][n][j]);
      }
    }
  }
}

extern "C" void kernel_launch(void* const* d_in, const int* in_sizes, int n_in,
                              void* d_out, int out_size, void* d_ws, size_t ws_size,
                              hipStream_t stream) {
  const float* x  = (const float*)d_in[0];
  const float* Wg = (const float*)d_in[1];
  const float* bg = (const float*)d_in[2];
  const float* W1 = (const float*)d_in[3];
  const float* b1 = (const float*)d_in[4];
  const float* W2 = (const float*)d_in[5];
  const float* b2 = (const float*)d_in[6];
  float* out = (float*)d_out;
  char* ws = (char*)d_ws;

  unsigned short* w1b   = (unsigned short*)(ws);             // 4,194,304 B
  unsigned short* w2b   = (unsigned short*)(ws + 4194304);   // 4,194,304 B
  int*   counts  = (int*)  (ws + 8388608);                   // 512 B (8 x 64B lines)
  int*   tok_ids = (int*)  (ws + 8389632);                   // 2,097,152 B
  float* tok_p   = (float*)(ws + 10486784);                  // 2,097,152 B

  hipMemsetAsync(counts, 0, 512, stream);
  cvt_w<<<4096, 256, 0, stream>>>(W1, W2, w1b, w2b);
  gate_kernel<<<T_TOKENS/GTB, 256, 0, stream>>>(x, Wg, bg, b2, counts, tok_ids, tok_p, out);
  ffn_kernel<<<dim3(T_TOKENS/MT, E_NUM), 128, 0, stream>>>(x, w1b, w2b, b1,
                                                           counts, tok_ids, tok_p, out);
}

// Round 3
// 421.552 us; speedup vs baseline: 6.5448x; 2.0834x over previous
//
#include <hip/hip_runtime.h>
#include <hip/hip_bf16.h>

#define T_TOKENS 65536
#define D_DIM 256
#define H_DIM 1024
#define E_NUM 8
#define MT 128
#define HC 64
#define NCHUNK 16              // H_DIM / HC
#define GTB 64                 // gate tokens per block

typedef __attribute__((ext_vector_type(4))) float f32x4;
typedef __attribute__((ext_vector_type(8))) short s16x8;
typedef __attribute__((address_space(3))) unsigned int lds_u32;
typedef const __attribute__((address_space(1))) unsigned int glb_u32;

#define MFMA __builtin_amdgcn_mfma_f32_16x16x32_bf16

__device__ __forceinline__ unsigned short f2bf(float f){
  union { float f; unsigned u; } v; v.f = f;
  unsigned r = v.u + 0x7FFFu + ((v.u >> 16) & 1u);
  return (unsigned short)(r >> 16);
}

__device__ __forceinline__ unsigned long long pack4(f32x4 v){
  return (unsigned long long)f2bf(v.x)
       | ((unsigned long long)f2bf(v.y) << 16)
       | ((unsigned long long)f2bf(v.z) << 32)
       | ((unsigned long long)f2bf(v.w) << 48);
}

// ---- convert W1/W2 -> bf16, pre-swizzled chunked image for global_load_lds ----
// chunk(e,c) = 64KB: [W1c: 64 h-rows x 256 d, row 512B, swz (r&7)<<4]
//            + [W2c at +32768: 256 d-rows x 64 h, row 128B, swz (d&7)<<4]
__global__ __launch_bounds__(256) void cvt_w(const float* __restrict__ W1,
                                             const float* __restrict__ W2,
                                             char* __restrict__ wsw){
  int i = blockIdx.x * 256 + threadIdx.x;          // unit of 4 floats
  const int N1 = (E_NUM * H_DIM * D_DIM) / 4;      // 524288
  unsigned long long pk;
  size_t off;
  if (i < N1){
    pk = pack4(((const f32x4*)W1)[i]);
    int idx = i << 2;
    int e  = idx >> 18;
    int h  = (idx >> 8) & (H_DIM - 1);
    int d0 = idx & (D_DIM - 1);
    int c = h >> 6, r = h & 63;
    off = ((size_t)(e * NCHUNK + c) << 16)
        + (size_t)(((r << 9) + (d0 << 1)) ^ ((r & 7) << 4));
  } else {
    pk = pack4(((const f32x4*)W2)[i - N1]);
    int idx = (i - N1) << 2;
    int e  = idx >> 18;
    int d  = (idx >> 10) & (D_DIM - 1);
    int h0 = idx & (H_DIM - 1);
    int c = h0 >> 6, hl = h0 & 63;
    off = ((size_t)(e * NCHUNK + c) << 16) + 32768
        + (size_t)(((d << 7) + (hl << 1)) ^ ((d & 7) << 4));
  }
  *(unsigned long long*)(wsw + off) = pk;
}

// ---- gate: scores, top-2, softmax, hierarchical-atomic routing,
//      out := p0*b2[e0]+p1*b2[e1] (doubles as out init) ----
__global__ __launch_bounds__(256) void gate_kernel(
    const float* __restrict__ x, const float* __restrict__ Wg,
    const float* __restrict__ bg, const float* __restrict__ b2,
    int* __restrict__ counts, int* __restrict__ tok_ids, float* __restrict__ tok_p,
    float* __restrict__ out)
{
  __shared__ int lcnt[E_NUM];
  __shared__ int lbase[E_NUM];
  __shared__ unsigned char aexp[GTB * 2];
  __shared__ short         apos[GTB * 2];
  __shared__ float         aprb[GTB * 2];

  int tid = threadIdx.x, wave = tid >> 6, lane = tid & 63;
  if (tid < E_NUM) lcnt[tid] = 0;
  __syncthreads();

  int t0 = blockIdx.x * GTB;
#pragma unroll 1
  for (int i = 0; i < GTB / 4; ++i){
    int tl = wave * (GTB / 4) + i;
    int t = t0 + tl;
    f32x4 xv = *(const f32x4*)(x + (size_t)t * D_DIM + 4*lane);
    float s[E_NUM];
#pragma unroll
    for (int e = 0; e < E_NUM; ++e){
      f32x4 w = *(const f32x4*)(Wg + e*D_DIM + 4*lane);
      s[e] = xv.x*w.x + xv.y*w.y + xv.z*w.z + xv.w*w.w;
    }
#pragma unroll
    for (int off = 32; off; off >>= 1){
#pragma unroll
      for (int e = 0; e < E_NUM; ++e) s[e] += __shfl_xor(s[e], off);
    }
#pragma unroll
    for (int e = 0; e < E_NUM; ++e) s[e] += bg[e];
    int e0 = 0; float v0 = s[0];
#pragma unroll
    for (int e = 1; e < E_NUM; ++e) if (s[e] > v0){ v0 = s[e]; e0 = e; }
    int e1 = -1; float v1 = -3.4e38f;
#pragma unroll
    for (int e = 0; e < E_NUM; ++e){
      if (e == e0) continue;
      if (s[e] > v1){ v1 = s[e]; e1 = e; }
    }
    float ex = __expf(v1 - v0);
    float inv = 1.f / (1.f + ex);
    float p0 = inv, p1 = ex * inv;
    if (lane == 0){
      int li = tl * 2;
      int pos0 = atomicAdd(&lcnt[e0], 1);
      int pos1 = atomicAdd(&lcnt[e1], 1);
      aexp[li]   = (unsigned char)e0; apos[li]   = (short)pos0; aprb[li]   = p0;
      aexp[li+1] = (unsigned char)e1; apos[li+1] = (short)pos1; aprb[li+1] = p1;
    }
    f32x4 bz0 = *(const f32x4*)(b2 + e0*D_DIM + 4*lane);
    f32x4 bz1 = *(const f32x4*)(b2 + e1*D_DIM + 4*lane);
    f32x4 o;
    o.x = p0*bz0.x + p1*bz1.x;
    o.y = p0*bz0.y + p1*bz1.y;
    o.z = p0*bz0.z + p1*bz1.z;
    o.w = p0*bz0.w + p1*bz1.w;
    *(f32x4*)(out + (size_t)t * D_DIM + 4*lane) = o;
  }
  __syncthreads();
  if (tid < E_NUM) lbase[tid] = atomicAdd(counts + tid*16, lcnt[tid]);
  __syncthreads();
  if (tid < GTB * 2){
    int t = t0 + (tid >> 1);
    int e = aexp[tid];
    int idx = lbase[e] + apos[tid];
    tok_ids[e*T_TOKENS + idx] = t;
    tok_p  [e*T_TOKENS + idx] = aprb[tid];
  }
}

// ---- grouped FFN: 128 tokens/block, 4 waves, H in 16 chunks of 64,
//      W chunks double-buffered in LDS via global_load_lds, A1 in registers ----
__global__ __launch_bounds__(256, 1) void ffn_kernel(
  const float* __restrict__ x, const char* __restrict__ wsw,
  const float* __restrict__ b1,
  const int* __restrict__ counts, const int* __restrict__ tok_ids,
  const float* __restrict__ tok_p, float* __restrict__ out)
{
  const int e    = blockIdx.x & 7;           // expert -> XCD pinning
  const int tile = blockIdx.x >> 3;
  const int cnt  = counts[e * 16];
  const int base = tile * MT;
  if (base >= cnt) return;

  __shared__ unsigned short Ws[2][32768];    // 2 x 64KB (W1c 32KB + W2c 32KB)
  __shared__ unsigned short Hs[MT * HC];     // 16KB, rows 128B, swz (m&7)<<4
  __shared__ float b1s[H_DIM];               // 4KB
  __shared__ int   sTok[MT];
  __shared__ float sP[MT];

  const int tid = threadIdx.x, wave = tid >> 6, lane = tid & 63;
  const int mrow = lane & 15, qj = lane >> 4, kq8 = qj * 8;
  const char* wexp = wsw + ((size_t)(e * NCHUNK) << 16);

  auto stage = [&](int c, unsigned short* dst){
    const char* src = wexp + ((size_t)c << 16);
#pragma unroll
    for (int i = 0; i < 16; ++i){
      int ub = i * 4096 + wave * 1024;       // wave-uniform LDS byte base
      __builtin_amdgcn_global_load_lds(
        (glb_u32*)(src + ub + lane * 16),
        (lds_u32*)((char*)dst + ub),
        16, 0, 0);
    }
  };

  if (tid < MT){
    int idx = base + tid;
    int tk = (idx < cnt) ? tok_ids[e*T_TOKENS + idx] : -1;
    sTok[tid] = tk;
    sP[tid]   = (idx < cnt) ? tok_p[e*T_TOKENS + idx] : 0.f;
  }
  *(f32x4*)&b1s[tid * 4] = ((const f32x4*)(b1 + e*H_DIM))[tid];
  __syncthreads();

  // issue chunk-0 staging, overlap with A-gather
  stage(0, &Ws[0][0]);

  // gather layer-1 A fragments into registers (32 tokens/wave, full D)
  s16x8 afr[2][8];
#pragma unroll
  for (int rb = 0; rb < 2; ++rb){
    int tk = sTok[wave*32 + rb*16 + mrow];
    const f32x4* src = (const f32x4*)(x + (size_t)(tk < 0 ? 0 : tk) * D_DIM);
#pragma unroll
    for (int k = 0; k < 8; ++k){
      f32x4 a = src[k*8 + qj*2];
      f32x4 b = src[k*8 + qj*2 + 1];
      s16x8 f;
      f[0]=(short)f2bf(a.x); f[1]=(short)f2bf(a.y); f[2]=(short)f2bf(a.z); f[3]=(short)f2bf(a.w);
      f[4]=(short)f2bf(b.x); f[5]=(short)f2bf(b.y); f[6]=(short)f2bf(b.z); f[7]=(short)f2bf(b.w);
      if (tk < 0) f = (s16x8)(short)0;
      afr[rb][k] = f;
    }
  }

  asm volatile("s_waitcnt vmcnt(0) lgkmcnt(0)" ::: "memory");
  __builtin_amdgcn_s_barrier();
  __builtin_amdgcn_sched_barrier(0);

  f32x4 yacc[8][4];
#pragma unroll
  for (int rb = 0; rb < 8; ++rb)
#pragma unroll
    for (int n = 0; n < 4; ++n) yacc[rb][n] = (f32x4){0.f,0.f,0.f,0.f};

  unsigned short* Wcur = &Ws[0][0];
  unsigned short* Wnxt = &Ws[1][0];

#pragma unroll 1
  for (int c = 0; c < NCHUNK; ++c){
    if (c + 1 < NCHUNK) stage(c + 1, Wnxt);   // in flight across barrier #1
    const char* W1c = (const char*)Wcur;
    const char* W2c = (const char*)Wcur + 32768;

    // ---- layer 1: h(32tok x 64h per wave) ----
    f32x4 hacc[2][4];
#pragma unroll
    for (int rb = 0; rb < 2; ++rb)
#pragma unroll
      for (int n = 0; n < 4; ++n) hacc[rb][n] = (f32x4){0.f,0.f,0.f,0.f};
#pragma unroll
    for (int k = 0; k < 8; ++k){
#pragma unroll
      for (int n = 0; n < 4; ++n){
        int hr = n*16 + mrow;
        s16x8 bfr = *(const s16x8*)(W1c + (((hr << 9) + ((k*32 + kq8) << 1)) ^ ((hr & 7) << 4)));
        hacc[0][n] = MFMA(afr[0][k], bfr, hacc[0][n], 0, 0, 0);
        hacc[1][n] = MFMA(afr[1][k], bfr, hacc[1][n], 0, 0, 0);
      }
    }
    // bias + relu -> Hs (wave-private rows)
#pragma unroll
    for (int rb = 0; rb < 2; ++rb)
#pragma unroll
      for (int n = 0; n < 4; ++n){
        float bias = b1s[c*HC + n*16 + mrow];
#pragma unroll
        for (int j = 0; j < 4; ++j){
          int m = wave*32 + rb*16 + qj*4 + j;
          float v = fmaxf(hacc[rb][n][j] + bias, 0.f);
          *(unsigned short*)((char*)Hs + (((m << 7) + ((n*16 + mrow) << 1)) ^ ((m & 7) << 4))) = f2bf(v);
        }
      }
    // barrier #1: Hs visible; staging stays in flight (no vmcnt drain)
    asm volatile("s_waitcnt lgkmcnt(0)" ::: "memory");
    __builtin_amdgcn_s_barrier();
    __builtin_amdgcn_sched_barrier(0);

    // ---- layer 2: y(128tok x 64d per wave) += h @ W2c^T ----
#pragma unroll
    for (int ks = 0; ks < 2; ++ks){
      s16x8 ha[8];
#pragma unroll
      for (int rb = 0; rb < 8; ++rb){
        int m = rb*16 + mrow;
        ha[rb] = *(const s16x8*)((char*)Hs + (((m << 7) + ((ks*32 + kq8) << 1)) ^ ((m & 7) << 4)));
      }
#pragma unroll
      for (int n = 0; n < 4; ++n){
        int d = wave*64 + n*16 + mrow;
        s16x8 bfr = *(const s16x8*)(W2c + (((d << 7) + ((ks*32 + kq8) << 1)) ^ ((d & 7) << 4)));
#pragma unroll
        for (int rb = 0; rb < 8; ++rb)
          yacc[rb][n] = MFMA(ha[rb], bfr, yacc[rb][n], 0, 0, 0);
      }
    }
    // barrier #2: drain staging (next chunk ready), protect Hs/Ws reuse
    asm volatile("s_waitcnt vmcnt(0) lgkmcnt(0)" ::: "memory");
    __builtin_amdgcn_s_barrier();
    __builtin_amdgcn_sched_barrier(0);

    unsigned short* t = Wcur; Wcur = Wnxt; Wnxt = t;
  }

  // ---- scatter: out[tok] += p * y ----
#pragma unroll
  for (int rb = 0; rb < 8; ++rb){
#pragma unroll
    for (int j = 0; j < 4; ++j){
      int m = rb*16 + qj*4 + j;
      int tk = sTok[m];
      if (tk < 0) continue;
      float p = sP[m];
#pragma unroll
      for (int n = 0; n < 4; ++n)
        atomicAdd(out + (size_t)tk * D_DIM + wave*64 + n*16 + mrow, p * yacc[rb][n][j]);
    }
  }
}

extern "C" void kernel_launch(void* const* d_in, const int* in_sizes, int n_in,
                              void* d_out, int out_size, void* d_ws, size_t ws_size,
                              hipStream_t stream) {
  const float* x  = (const float*)d_in[0];
  const float* Wg = (const float*)d_in[1];
  const float* bg = (const float*)d_in[2];
  const float* W1 = (const float*)d_in[3];
  const float* b1 = (const float*)d_in[4];
  const float* W2 = (const float*)d_in[5];
  const float* b2 = (const float*)d_in[6];
  float* out = (float*)d_out;
  char* ws = (char*)d_ws;

  char*  wsw     = ws;                        // 8,388,608 B swizzled weights
  int*   counts  = (int*)  (ws + 8388608);    // 512 B (8 x 64B lines)
  int*   tok_ids = (int*)  (ws + 8389632);    // 2,097,152 B
  float* tok_p   = (float*)(ws + 10486784);   // 2,097,152 B

  hipMemsetAsync(counts, 0, 512, stream);
  cvt_w<<<4096, 256, 0, stream>>>(W1, W2, wsw);
  gate_kernel<<<T_TOKENS/GTB, 256, 0, stream>>>(x, Wg, bg, b2, counts, tok_ids, tok_p, out);
  ffn_kernel<<<E_NUM * (T_TOKENS/MT), 256, 0, stream>>>(x, wsw, b1,
                                                        counts, tok_ids, tok_p, out);
}

// Round 4
// 380.635 us; speedup vs baseline: 7.2483x; 1.1075x over previous
//
#include <hip/hip_runtime.h>
#include <hip/hip_bf16.h>

#define T_TOKENS 65536
#define D_DIM 256
#define H_DIM 1024
#define E_NUM 8
#define MT 128
#define HC 32
#define NCHUNK 32              // H_DIM / HC
#define GTB 64                 // gate tokens per block

typedef __attribute__((ext_vector_type(4))) float f32x4;
typedef __attribute__((ext_vector_type(8))) short s16x8;
typedef __attribute__((ext_vector_type(4))) unsigned short u16x4;
typedef __attribute__((address_space(3))) unsigned int lds_u32;
typedef const __attribute__((address_space(1))) unsigned int glb_u32;

#define MFMA __builtin_amdgcn_mfma_f32_16x16x32_bf16

__device__ __forceinline__ unsigned short f2bf(float f){
  union { float f; unsigned u; } v; v.f = f;
  unsigned r = v.u + 0x7FFFu + ((v.u >> 16) & 1u);
  return (unsigned short)(r >> 16);
}
__device__ __forceinline__ float bf2f(unsigned short h){
  return __uint_as_float((unsigned)h << 16);
}
__device__ __forceinline__ unsigned long long pack4(f32x4 v){
  return (unsigned long long)f2bf(v.x)
       | ((unsigned long long)f2bf(v.y) << 16)
       | ((unsigned long long)f2bf(v.z) << 32)
       | ((unsigned long long)f2bf(v.w) << 48);
}

// ---- convert W1/W2 -> bf16, pre-swizzled 32KB-chunk image for global_load_lds
// chunk(e,c): [W1c: 32 h-rows x 256 d, row 512B, swz (r&7)<<4]
//           + [W2c at +16384: 256 d-rows x 32 h, row 64B, swz (d&3)<<4]
__global__ __launch_bounds__(256) void cvt_w(const float* __restrict__ W1,
                                             const float* __restrict__ W2,
                                             char* __restrict__ wsw){
  int i = blockIdx.x * 256 + threadIdx.x;          // unit of 4 floats
  const int N1 = (E_NUM * H_DIM * D_DIM) / 4;      // 524288
  unsigned long long pk;
  size_t off;
  if (i < N1){
    pk = pack4(((const f32x4*)W1)[i]);
    int idx = i << 2;
    int e  = idx >> 18;
    int h  = (idx >> 8) & (H_DIM - 1);
    int d0 = idx & (D_DIM - 1);
    int c = h >> 5, r = h & 31;
    off = ((size_t)(e * NCHUNK + c) << 15)
        + (size_t)(((r << 9) + (d0 << 1)) ^ ((r & 7) << 4));
  } else {
    pk = pack4(((const f32x4*)W2)[i - N1]);
    int idx = (i - N1) << 2;
    int e  = idx >> 18;
    int d  = (idx >> 10) & (D_DIM - 1);
    int h0 = idx & (H_DIM - 1);
    int c = h0 >> 5, hl = h0 & 31;
    off = ((size_t)(e * NCHUNK + c) << 15) + 16384
        + (size_t)(((d << 6) + (hl << 1)) ^ ((d & 3) << 4));
  }
  *(unsigned long long*)(wsw + off) = pk;
}

// ---- gate: scores, top-2, softmax, hierarchical-atomic routing, rrec ----
__global__ __launch_bounds__(256) void gate_kernel(
    const float* __restrict__ x, const float* __restrict__ Wg,
    const float* __restrict__ bg,
    int* __restrict__ counts, int* __restrict__ tok_ids, float* __restrict__ rrec)
{
  __shared__ int lcnt[E_NUM];
  __shared__ int lbase[E_NUM];
  __shared__ unsigned char aexp[GTB * 2];
  __shared__ short         apos[GTB * 2];

  int tid = threadIdx.x, wave = tid >> 6, lane = tid & 63;
  if (tid < E_NUM) lcnt[tid] = 0;
  __syncthreads();

  int t0 = blockIdx.x * GTB;
#pragma unroll 1
  for (int i = 0; i < GTB / 4; ++i){
    int tl = wave * (GTB / 4) + i;
    int t = t0 + tl;
    f32x4 xv = *(const f32x4*)(x + (size_t)t * D_DIM + 4*lane);
    float s[E_NUM];
#pragma unroll
    for (int e = 0; e < E_NUM; ++e){
      f32x4 w = *(const f32x4*)(Wg + e*D_DIM + 4*lane);
      s[e] = xv.x*w.x + xv.y*w.y + xv.z*w.z + xv.w*w.w;
    }
#pragma unroll
    for (int off = 32; off; off >>= 1){
#pragma unroll
      for (int e = 0; e < E_NUM; ++e) s[e] += __shfl_xor(s[e], off);
    }
#pragma unroll
    for (int e = 0; e < E_NUM; ++e) s[e] += bg[e];
    int e0 = 0; float v0 = s[0];
#pragma unroll
    for (int e = 1; e < E_NUM; ++e) if (s[e] > v0){ v0 = s[e]; e0 = e; }
    int e1 = -1; float v1 = -3.4e38f;
#pragma unroll
    for (int e = 0; e < E_NUM; ++e){
      if (e == e0) continue;
      if (s[e] > v1){ v1 = s[e]; e1 = e; }
    }
    float ex = __expf(v1 - v0);
    float inv = 1.f / (1.f + ex);
    float p0 = inv, p1 = ex * inv;
    if (lane == 0){
      int li = tl * 2;
      int pos0 = atomicAdd(&lcnt[e0], 1);
      int pos1 = atomicAdd(&lcnt[e1], 1);
      aexp[li]   = (unsigned char)e0; apos[li]   = (short)pos0;
      aexp[li+1] = (unsigned char)e1; apos[li+1] = (short)pos1;
      f32x4 rr; rr.x = p0; rr.y = p1; rr.z = (float)e0; rr.w = (float)e1;
      *(f32x4*)(rrec + (size_t)t * 4) = rr;
    }
  }
  __syncthreads();
  if (tid < E_NUM) lbase[tid] = atomicAdd(counts + tid*16, lcnt[tid]);
  __syncthreads();
  if (tid < GTB * 2){
    int t = t0 + (tid >> 1);
    int e = aexp[tid];
    int idx = lbase[e] + apos[tid];
    tok_ids[e*T_TOKENS + idx] = t | ((tid & 1) << 16);   // token | which-bit
  }
}

// ---- grouped FFN: 128 tokens/block, 4 waves, H in 32 chunks of 32,
//      weights double-buffered in LDS (64KB) -> 2 blocks/CU,
//      y stored unscaled as bf16 to slot 2*tok+which inside d_out ----
__global__ __launch_bounds__(256, 2) void ffn_kernel(
  const float* __restrict__ x, const char* __restrict__ wsw,
  const float* __restrict__ b1,
  const int* __restrict__ counts, const int* __restrict__ tok_ids,
  unsigned short* __restrict__ yslot)
{
  const int e    = blockIdx.x & 7;           // expert -> XCD pinning
  const int tile = blockIdx.x >> 3;
  const int cnt  = counts[e * 16];
  const int base = tile * MT;
  if (base >= cnt) return;

  __shared__ unsigned short Ws[2][16384];    // 2 x 32KB chunk (W1c 16K + W2c 16K)
  __shared__ unsigned short Hs[MT * HC];     // 8KB, rows 64B, swz (m&3)<<4
  __shared__ float b1s[H_DIM];               // 4KB
  __shared__ int   sTok[MT];

  const int tid = threadIdx.x, wave = tid >> 6, lane = tid & 63;
  const int mrow = lane & 15, qj = lane >> 4, kq8 = qj * 8;
  const char* wexp = wsw + ((size_t)(e * NCHUNK) << 15);

  auto stage = [&](int c, unsigned short* dst){
    const char* src = wexp + ((size_t)c << 15);
#pragma unroll
    for (int i = 0; i < 8; ++i){
      int ub = i * 4096 + wave * 1024;       // wave-uniform LDS byte base
      __builtin_amdgcn_global_load_lds(
        (glb_u32*)(src + ub + lane * 16),
        (lds_u32*)((char*)dst + ub),
        16, 0, 0);
    }
  };

  if (tid < MT){
    int idx = base + tid;
    sTok[tid] = (idx < cnt) ? tok_ids[e*T_TOKENS + idx] : -1;
  }
  *(f32x4*)&b1s[tid * 4] = ((const f32x4*)(b1 + e*H_DIM))[tid];
  __syncthreads();

  // issue chunk-0 staging, overlap with A-gather
  stage(0, &Ws[0][0]);

  // gather layer-1 A fragments into registers (32 tokens/wave, full D)
  s16x8 afr[2][8];
#pragma unroll
  for (int rb = 0; rb < 2; ++rb){
    int ent = sTok[wave*32 + rb*16 + mrow];
    int tk = ent & 0xFFFF;
    const f32x4* src = (const f32x4*)(x + (size_t)(ent < 0 ? 0 : tk) * D_DIM);
#pragma unroll
    for (int k = 0; k < 8; ++k){
      f32x4 a = src[k*8 + qj*2];
      f32x4 b = src[k*8 + qj*2 + 1];
      s16x8 f;
      f[0]=(short)f2bf(a.x); f[1]=(short)f2bf(a.y); f[2]=(short)f2bf(a.z); f[3]=(short)f2bf(a.w);
      f[4]=(short)f2bf(b.x); f[5]=(short)f2bf(b.y); f[6]=(short)f2bf(b.z); f[7]=(short)f2bf(b.w);
      if (ent < 0) f = (s16x8)(short)0;
      afr[rb][k] = f;
    }
  }

  asm volatile("s_waitcnt vmcnt(0) lgkmcnt(0)" ::: "memory");
  __builtin_amdgcn_s_barrier();
  __builtin_amdgcn_sched_barrier(0);

  f32x4 yacc[8][4];
#pragma unroll
  for (int rb = 0; rb < 8; ++rb)
#pragma unroll
    for (int n = 0; n < 4; ++n) yacc[rb][n] = (f32x4){0.f,0.f,0.f,0.f};

  unsigned short* Wcur = &Ws[0][0];
  unsigned short* Wnxt = &Ws[1][0];

#pragma unroll 1
  for (int c = 0; c < NCHUNK; ++c){
    if (c + 1 < NCHUNK) stage(c + 1, Wnxt);   // in flight across barrier #1
    const char* W1c = (const char*)Wcur;
    const char* W2c = (const char*)Wcur + 16384;

    // ---- layer 1: h(32tok x 32h per wave) ----
    f32x4 hacc[2][2];
#pragma unroll
    for (int rb = 0; rb < 2; ++rb)
#pragma unroll
      for (int n = 0; n < 2; ++n) hacc[rb][n] = (f32x4){0.f,0.f,0.f,0.f};
#pragma unroll
    for (int k = 0; k < 8; ++k){
#pragma unroll
      for (int n = 0; n < 2; ++n){
        int hr = n*16 + mrow;
        s16x8 bfr = *(const s16x8*)(W1c + (((hr << 9) + (k*64 + qj*16)) ^ ((hr & 7) << 4)));
        hacc[0][n] = MFMA(afr[0][k], bfr, hacc[0][n], 0, 0, 0);
        hacc[1][n] = MFMA(afr[1][k], bfr, hacc[1][n], 0, 0, 0);
      }
    }
    // bias + relu -> Hs (wave-private rows)
#pragma unroll
    for (int rb = 0; rb < 2; ++rb)
#pragma unroll
      for (int n = 0; n < 2; ++n){
        float bias = b1s[c*HC + n*16 + mrow];
#pragma unroll
        for (int j = 0; j < 4; ++j){
          int m = wave*32 + rb*16 + qj*4 + j;
          float v = fmaxf(hacc[rb][n][j] + bias, 0.f);
          *(unsigned short*)((char*)Hs + (((m << 6) + ((n*16 + mrow) << 1)) ^ ((m & 3) << 4))) = f2bf(v);
        }
      }
    // barrier #1: Hs visible; staging stays in flight (no vmcnt drain)
    asm volatile("s_waitcnt lgkmcnt(0)" ::: "memory");
    __builtin_amdgcn_s_barrier();
    __builtin_amdgcn_sched_barrier(0);

    // ---- layer 2: y(128tok x 64d per wave) += h @ W2c^T ----
    {
      s16x8 ha[8];
#pragma unroll
      for (int rb = 0; rb < 8; ++rb){
        int m = rb*16 + mrow;
        ha[rb] = *(const s16x8*)((char*)Hs + (((m << 6) + (qj << 4)) ^ ((m & 3) << 4)));
      }
#pragma unroll
      for (int n = 0; n < 4; ++n){
        int d = wave*64 + n*16 + mrow;
        s16x8 bfr = *(const s16x8*)(W2c + (((d << 6) + (qj << 4)) ^ ((d & 3) << 4)));
#pragma unroll
        for (int rb = 0; rb < 8; ++rb)
          yacc[rb][n] = MFMA(ha[rb], bfr, yacc[rb][n], 0, 0, 0);
      }
    }
    // barrier #2: drain staging (next chunk ready), protect Hs/Ws reuse
    asm volatile("s_waitcnt vmcnt(0) lgkmcnt(0)" ::: "memory");
    __builtin_amdgcn_s_barrier();
    __builtin_amdgcn_sched_barrier(0);

    unsigned short* t = Wcur; Wcur = Wnxt; Wnxt = t;
  }

  // ---- scatter: yslot[2*tok+which][col] = bf16(y) (unscaled, no atomics) ----
#pragma unroll
  for (int rb = 0; rb < 8; ++rb){
#pragma unroll
    for (int j = 0; j < 4; ++j){
      int m = rb*16 + qj*4 + j;
      int ent = sTok[m];
      if (ent < 0) continue;
      int slot = ((ent & 0xFFFF) << 1) | ((ent >> 16) & 1);
      size_t sb = (size_t)slot * 256 + wave*64;
#pragma unroll
      for (int n = 0; n < 4; ++n)
        yslot[sb + n*16 + mrow] = f2bf(yacc[rb][n][j]);
    }
  }
}

// ---- combine: out[t] = p0*(y0+b2[e0]) + p1*(y1+b2[e1]); in-place over slots ----
__global__ __launch_bounds__(256) void combine_kernel(
    const float* __restrict__ rrec, const float* __restrict__ b2,
    float* __restrict__ out)
{
  int t = blockIdx.x * 4 + (threadIdx.x >> 6);
  int lane = threadIdx.x & 63;
  f32x4 rr = *(const f32x4*)(rrec + (size_t)t * 4);
  float p0 = rr.x, p1 = rr.y;
  int e0 = (int)rr.z, e1 = (int)rr.w;
  const u16x4* s0 = (const u16x4*)((const unsigned short*)out + (size_t)t * 512);
  u16x4 a = s0[lane];        // slot 2t   : cols lane*4..+3
  u16x4 b = s0[64 + lane];   // slot 2t+1
  f32x4 z0 = *(const f32x4*)(b2 + e0*D_DIM + 4*lane);
  f32x4 z1 = *(const f32x4*)(b2 + e1*D_DIM + 4*lane);
  f32x4 o;
  o.x = p0*(bf2f(a.x) + z0.x) + p1*(bf2f(b.x) + z1.x);
  o.y = p0*(bf2f(a.y) + z0.y) + p1*(bf2f(b.y) + z1.y);
  o.z = p0*(bf2f(a.z) + z0.z) + p1*(bf2f(b.z) + z1.z);
  o.w = p0*(bf2f(a.w) + z0.w) + p1*(bf2f(b.w) + z1.w);
  *(f32x4*)(out + (size_t)t * D_DIM + 4*lane) = o;
}

extern "C" void kernel_launch(void* const* d_in, const int* in_sizes, int n_in,
                              void* d_out, int out_size, void* d_ws, size_t ws_size,
                              hipStream_t stream) {
  const float* x  = (const float*)d_in[0];
  const float* Wg = (const float*)d_in[1];
  const float* bg = (const float*)d_in[2];
  const float* W1 = (const float*)d_in[3];
  const float* b1 = (const float*)d_in[4];
  const float* W2 = (const float*)d_in[5];
  const float* b2 = (const float*)d_in[6];
  float* out = (float*)d_out;
  char* ws = (char*)d_ws;

  char*  wsw     = ws;                        // 8,388,608 B swizzled weights
  int*   counts  = (int*)  (ws + 8388608);    // 512 B (8 x 64B lines)
  int*   tok_ids = (int*)  (ws + 8389632);    // 2,097,152 B
  float* rrec    = (float*)(ws + 10486784);   // 1,048,576 B (f32x4 per token)

  hipMemsetAsync(counts, 0, 512, stream);
  cvt_w<<<4096, 256, 0, stream>>>(W1, W2, wsw);
  gate_kernel<<<T_TOKENS/GTB, 256, 0, stream>>>(x, Wg, bg, counts, tok_ids, rrec);
  ffn_kernel<<<E_NUM * (T_TOKENS/MT), 256, 0, stream>>>(x, wsw, b1, counts, tok_ids,
                                                        (unsigned short*)d_out);
  combine_kernel<<<T_TOKENS/4, 256, 0, stream>>>(rrec, b2, out);
}

// Round 5
// 258.324 us; speedup vs baseline: 10.6803x; 1.4735x over previous
//
#include <hip/hip_runtime.h>
#include <hip/hip_bf16.h>

#define T_TOKENS 65536
#define D_DIM 256
#define H_DIM 1024
#define E_NUM 8
#define MT 128
#define HC 32
#define NCHUNK 32              // H_DIM / HC
#define GTB 64                 // gate tokens per block

typedef __attribute__((ext_vector_type(4))) float f32x4;
typedef __attribute__((ext_vector_type(8))) short s16x8;
typedef __attribute__((ext_vector_type(4))) unsigned int u32x4;
typedef __attribute__((ext_vector_type(4))) unsigned short u16x4;
typedef __attribute__((address_space(3))) unsigned int lds_u32;
typedef const __attribute__((address_space(1))) unsigned int glb_u32;

#define MFMA __builtin_amdgcn_mfma_f32_16x16x32_bf16

__device__ __forceinline__ unsigned short f2bf(float f){
  union { float f; unsigned u; } v; v.f = f;
  unsigned r = v.u + 0x7FFFu + ((v.u >> 16) & 1u);
  return (unsigned short)(r >> 16);
}
__device__ __forceinline__ float bf2f(unsigned short h){
  return __uint_as_float((unsigned)h << 16);
}
__device__ __forceinline__ unsigned cvtpk(float lo, float hi){
  unsigned r;
  asm("v_cvt_pk_bf16_f32 %0, %1, %2" : "=v"(r) : "v"(lo), "v"(hi));
  return r;
}
__device__ __forceinline__ unsigned long long pack4(f32x4 v){
  return (unsigned long long)f2bf(v.x)
       | ((unsigned long long)f2bf(v.y) << 16)
       | ((unsigned long long)f2bf(v.z) << 32)
       | ((unsigned long long)f2bf(v.w) << 48);
}

// one 4-float unit of weight conversion into the swizzled chunk image.
// chunk(e,c) = 32KB: [W1c: 32 h-rows x 256 d, row 512B, swz (h&7)<<4]
//  + [W2p at +16384: 256 d-rows x 32 h-slots, row 64B, slot s=qj*8+mi*4+j
//     holding W2[d][mi*16+qj*4+j], swz ((d>>1)&3)<<4]
__device__ __forceinline__ void cvt_unit(int i, const float* __restrict__ W1,
                                         const float* __restrict__ W2,
                                         char* __restrict__ wsw){
  const int N1 = (E_NUM * H_DIM * D_DIM) / 4;      // 524288
  unsigned long long pk;
  size_t off;
  if (i < N1){
    pk = pack4(((const f32x4*)W1)[i]);
    int idx = i << 2;
    int e  = idx >> 18;
    int h  = (idx >> 8) & (H_DIM - 1);
    int d0 = idx & (D_DIM - 1);
    int c = h >> 5, r = h & 31;
    off = ((size_t)(e * NCHUNK + c) << 15)
        + (size_t)(((r << 9) + (d0 << 1)) ^ ((r & 7) << 4));
  } else {
    pk = pack4(((const f32x4*)W2)[i - N1]);
    int idx = (i - N1) << 2;
    int e  = idx >> 18;
    int d  = (idx >> 10) & (D_DIM - 1);
    int h0 = idx & (H_DIM - 1);
    int c  = h0 >> 5;
    int mi = (h0 >> 4) & 1, qjs = (h0 >> 2) & 3;
    int s2 = qjs * 16 + mi * 8;                    // byte offset of the 8B slot group
    off = ((size_t)(e * NCHUNK + c) << 15) + 16384
        + (size_t)((d << 6) + (s2 ^ (((d >> 1) & 3) << 4)));
  }
  *(unsigned long long*)(wsw + off) = pk;
}

// ---- gate (+fused weight conversion): scores, top-2, softmax, routing ----
__global__ __launch_bounds__(256) void gate_kernel(
    const float* __restrict__ x, const float* __restrict__ Wg,
    const float* __restrict__ bg,
    const float* __restrict__ W1, const float* __restrict__ W2,
    char* __restrict__ wsw,
    int* __restrict__ counts, int* __restrict__ tok_ids, float* __restrict__ rrec)
{
  __shared__ int lcnt[E_NUM];
  __shared__ int lbase[E_NUM];
  __shared__ unsigned char aexp[GTB * 2];
  __shared__ short         apos[GTB * 2];

  int tid = threadIdx.x, wave = tid >> 6, lane = tid & 63;

  // fused weight conversion: 4 units per thread
  int gthr = blockIdx.x * 256 + tid;
#pragma unroll
  for (int j = 0; j < 4; ++j)
    cvt_unit(gthr + j * ((T_TOKENS / GTB) * 256), W1, W2, wsw);

  if (tid < E_NUM) lcnt[tid] = 0;
  __syncthreads();

  int t0 = blockIdx.x * GTB;
#pragma unroll 1
  for (int i = 0; i < GTB / 4; ++i){
    int tl = wave * (GTB / 4) + i;
    int t = t0 + tl;
    f32x4 xv = *(const f32x4*)(x + (size_t)t * D_DIM + 4*lane);
    float s[E_NUM];
#pragma unroll
    for (int e = 0; e < E_NUM; ++e){
      f32x4 w = *(const f32x4*)(Wg + e*D_DIM + 4*lane);
      s[e] = xv.x*w.x + xv.y*w.y + xv.z*w.z + xv.w*w.w;
    }
#pragma unroll
    for (int off = 32; off; off >>= 1){
#pragma unroll
      for (int e = 0; e < E_NUM; ++e) s[e] += __shfl_xor(s[e], off);
    }
#pragma unroll
    for (int e = 0; e < E_NUM; ++e) s[e] += bg[e];
    int e0 = 0; float v0 = s[0];
#pragma unroll
    for (int e = 1; e < E_NUM; ++e) if (s[e] > v0){ v0 = s[e]; e0 = e; }
    int e1 = -1; float v1 = -3.4e38f;
#pragma unroll
    for (int e = 0; e < E_NUM; ++e){
      if (e == e0) continue;
      if (s[e] > v1){ v1 = s[e]; e1 = e; }
    }
    float ex = __expf(v1 - v0);
    float inv = 1.f / (1.f + ex);
    float p0 = inv, p1 = ex * inv;
    if (lane == 0){
      int li = tl * 2;
      int pos0 = atomicAdd(&lcnt[e0], 1);
      int pos1 = atomicAdd(&lcnt[e1], 1);
      aexp[li]   = (unsigned char)e0; apos[li]   = (short)pos0;
      aexp[li+1] = (unsigned char)e1; apos[li+1] = (short)pos1;
      f32x4 rr; rr.x = p0; rr.y = p1; rr.z = (float)e0; rr.w = (float)e1;
      *(f32x4*)(rrec + (size_t)t * 4) = rr;
    }
  }
  __syncthreads();
  if (tid < E_NUM) lbase[tid] = atomicAdd(counts + tid*16, lcnt[tid]);
  __syncthreads();
  if (tid < GTB * 2){
    int t = t0 + (tid >> 1);
    int e = aexp[tid];
    int idx = lbase[e] + apos[tid];
    tok_ids[e*T_TOKENS + idx] = t | ((tid & 1) << 16);   // token | which-bit
  }
}

// ---- grouped FFN: swapped-operand L1, h stays in registers (k-slot permuted
//      W2 image), one barrier per chunk, weights double-buffered via
//      global_load_lds. 128 tokens/block, 4 waves x 32 tokens. ----
__global__ __launch_bounds__(256, 2) void ffn_kernel(
  const float* __restrict__ x, const char* __restrict__ wsw,
  const float* __restrict__ b1,
  const int* __restrict__ counts, const int* __restrict__ tok_ids,
  unsigned short* __restrict__ yslot)
{
  const int e    = blockIdx.x & 7;           // expert -> XCD pinning
  const int tile = blockIdx.x >> 3;
  const int cnt  = counts[e * 16];
  const int base = tile * MT;
  if (base >= cnt) return;

  __shared__ __align__(1024) unsigned short Ws[2][16384];  // 2 x 32KB
  __shared__ __align__(16)   float b1s[H_DIM];             // 4KB
  __shared__ int sTok[MT];

  const int tid = threadIdx.x, wave = tid >> 6, lane = tid & 63;
  const int mrow = lane & 15, qj = lane >> 4;
  const char* wexp = wsw + ((size_t)(e * NCHUNK) << 15);

  auto stage = [&](int c, int buf){
    const char* src = wexp + ((size_t)c << 15);
    char* dst = (char*)&Ws[buf][0];
#pragma unroll
    for (int i = 0; i < 8; ++i){
      int ub = i * 4096 + wave * 1024;       // wave-uniform LDS byte base
      __builtin_amdgcn_global_load_lds(
        (glb_u32*)(src + ub + lane * 16),
        (lds_u32*)(dst + ub), 16, 0, 0);
    }
  };

  if (tid < MT){
    int idx = base + tid;
    sTok[tid] = (idx < cnt) ? tok_ids[e*T_TOKENS + idx] : -1;
  }
  *(f32x4*)&b1s[tid * 4] = ((const f32x4*)(b1 + e*H_DIM))[tid];
  __syncthreads();

  stage(0, 0);

  // gather x B-fragments into registers (32 tokens/wave, full D)
  s16x8 afr[2][8];
#pragma unroll
  for (int ti = 0; ti < 2; ++ti){
    int ent = sTok[wave*32 + ti*16 + mrow];
    int tk = ent & 0xFFFF;
    const f32x4* src = (const f32x4*)(x + (size_t)(ent < 0 ? 0 : tk) * D_DIM);
#pragma unroll
    for (int k = 0; k < 8; ++k){
      f32x4 a = src[k*8 + qj*2];
      f32x4 b = src[k*8 + qj*2 + 1];
      s16x8 f;
      f[0]=(short)f2bf(a.x); f[1]=(short)f2bf(a.y); f[2]=(short)f2bf(a.z); f[3]=(short)f2bf(a.w);
      f[4]=(short)f2bf(b.x); f[5]=(short)f2bf(b.y); f[6]=(short)f2bf(b.z); f[7]=(short)f2bf(b.w);
      if (ent < 0) f = (s16x8)(short)0;
      afr[ti][k] = f;
    }
  }

  // per-lane LDS byte bases (swizzles are lane-constant)
  const int w1base = mrow*512 + ((qj*16) ^ ((mrow & 3) << 4)); // + mi*8192 + ((ks^sb)<<6)
  const int w1sb   = (mrow >> 2) & 1;
  const int w2base = 16384 + mrow*64 + ((qj*16) ^ (((mrow >> 1) & 3) << 4)); // + m*1024

  asm volatile("s_waitcnt vmcnt(0) lgkmcnt(0)" ::: "memory");
  __builtin_amdgcn_s_barrier();

  f32x4 yacc[16][2];
#pragma unroll
  for (int m = 0; m < 16; ++m){
    yacc[m][0] = (f32x4){0.f,0.f,0.f,0.f};
    yacc[m][1] = (f32x4){0.f,0.f,0.f,0.f};
  }

  int buf = 0;
#pragma unroll 1
  for (int c = 0; c < NCHUNK; ++c){
    if (c + 1 < NCHUNK) stage(c + 1, buf ^ 1);   // in flight across the chunk
    const char* Wb = (const char*)&Ws[buf][0];

    // ---- layer 1 (swapped): hacc[mi][ti] = W1 x^T, D[h][token] ----
    f32x4 hacc[2][2];
    hacc[0][0] = (f32x4){0.f,0.f,0.f,0.f}; hacc[0][1] = (f32x4){0.f,0.f,0.f,0.f};
    hacc[1][0] = (f32x4){0.f,0.f,0.f,0.f}; hacc[1][1] = (f32x4){0.f,0.f,0.f,0.f};
#pragma unroll
    for (int ks = 0; ks < 8; ++ks){
      int ko = ((ks ^ w1sb) << 6);
      s16x8 w1a = *(const s16x8*)(Wb + w1base + ko);
      s16x8 w1b = *(const s16x8*)(Wb + 8192 + w1base + ko);
      hacc[0][0] = MFMA(w1a, afr[0][ks], hacc[0][0], 0, 0, 0);
      hacc[0][1] = MFMA(w1a, afr[1][ks], hacc[0][1], 0, 0, 0);
      hacc[1][0] = MFMA(w1b, afr[0][ks], hacc[1][0], 0, 0, 0);
      hacc[1][1] = MFMA(w1b, afr[1][ks], hacc[1][1], 0, 0, 0);
    }

    // ---- bias + relu + pack to bf16 B-fragments (in registers) ----
    f32x4 bv0 = *(const f32x4*)&b1s[c*32 + qj*4];
    f32x4 bv1 = *(const f32x4*)&b1s[c*32 + 16 + qj*4];
    s16x8 pb0, pb1;
    {
      f32x4 h0 = hacc[0][0], h1 = hacc[1][0];
      h0.x = fmaxf(h0.x + bv0.x, 0.f); h0.y = fmaxf(h0.y + bv0.y, 0.f);
      h0.z = fmaxf(h0.z + bv0.z, 0.f); h0.w = fmaxf(h0.w + bv0.w, 0.f);
      h1.x = fmaxf(h1.x + bv1.x, 0.f); h1.y = fmaxf(h1.y + bv1.y, 0.f);
      h1.z = fmaxf(h1.z + bv1.z, 0.f); h1.w = fmaxf(h1.w + bv1.w, 0.f);
      u32x4 pw;
      pw.x = cvtpk(h0.x, h0.y); pw.y = cvtpk(h0.z, h0.w);
      pw.z = cvtpk(h1.x, h1.y); pw.w = cvtpk(h1.z, h1.w);
      pb0 = __builtin_bit_cast(s16x8, pw);
    }
    {
      f32x4 h0 = hacc[0][1], h1 = hacc[1][1];
      h0.x = fmaxf(h0.x + bv0.x, 0.f); h0.y = fmaxf(h0.y + bv0.y, 0.f);
      h0.z = fmaxf(h0.z + bv0.z, 0.f); h0.w = fmaxf(h0.w + bv0.w, 0.f);
      h1.x = fmaxf(h1.x + bv1.x, 0.f); h1.y = fmaxf(h1.y + bv1.y, 0.f);
      h1.z = fmaxf(h1.z + bv1.z, 0.f); h1.w = fmaxf(h1.w + bv1.w, 0.f);
      u32x4 pw;
      pw.x = cvtpk(h0.x, h0.y); pw.y = cvtpk(h0.z, h0.w);
      pw.z = cvtpk(h1.x, h1.y); pw.w = cvtpk(h1.z, h1.w);
      pb1 = __builtin_bit_cast(s16x8, pw);
    }

    // ---- layer 2 (swapped, k-slot permuted W2): yacc[m][ti] D[d][token] ----
#pragma unroll
    for (int m = 0; m < 16; ++m){
      s16x8 w2f = *(const s16x8*)(Wb + w2base + m*1024);
      yacc[m][0] = MFMA(w2f, pb0, yacc[m][0], 0, 0, 0);
      yacc[m][1] = MFMA(w2f, pb1, yacc[m][1], 0, 0, 0);
    }

    // one barrier per chunk: next chunk staged + this buffer free for reuse
    asm volatile("s_waitcnt vmcnt(0)" ::: "memory");
    __builtin_amdgcn_s_barrier();
    buf ^= 1;
  }

  // ---- store: yslot[2*tok+which][d] = bf16(y), packed b32, no atomics ----
#pragma unroll
  for (int ti = 0; ti < 2; ++ti){
    int ent = sTok[wave*32 + ti*16 + mrow];
    if (ent < 0) continue;
    int slot = ((ent & 0xFFFF) << 1) | ((ent >> 16) & 1);
    unsigned short* dst = yslot + (size_t)slot * 256;
#pragma unroll
    for (int m = 0; m < 16; ++m){
      unsigned lo = cvtpk(yacc[m][ti][0], yacc[m][ti][1]);
      unsigned hi = cvtpk(yacc[m][ti][2], yacc[m][ti][3]);
      *(unsigned*)(dst + m*16 + qj*4)     = lo;   // d = m*16 + qj*4 + {0,1}
      *(unsigned*)(dst + m*16 + qj*4 + 2) = hi;   // d = ... + {2,3}
    }
  }
}

// ---- combine: out[t] = p0*(y0+b2[e0]) + p1*(y1+b2[e1]); in-place over slots ----
__global__ __launch_bounds__(256) void combine_kernel(
    const float* __restrict__ rrec, const float* __restrict__ b2,
    float* __restrict__ out)
{
  int t = blockIdx.x * 4 + (threadIdx.x >> 6);
  int lane = threadIdx.x & 63;
  f32x4 rr = *(const f32x4*)(rrec + (size_t)t * 4);
  float p0 = rr.x, p1 = rr.y;
  int e0 = (int)rr.z, e1 = (int)rr.w;
  const u16x4* s0 = (const u16x4*)((const unsigned short*)out + (size_t)t * 512);
  u16x4 a = s0[lane];        // slot 2t   : cols lane*4..+3
  u16x4 b = s0[64 + lane];   // slot 2t+1
  f32x4 z0 = *(const f32x4*)(b2 + e0*D_DIM + 4*lane);
  f32x4 z1 = *(const f32x4*)(b2 + e1*D_DIM + 4*lane);
  f32x4 o;
  o.x = p0*(bf2f(a.x) + z0.x) + p1*(bf2f(b.x) + z1.x);
  o.y = p0*(bf2f(a.y) + z0.y) + p1*(bf2f(b.y) + z1.y);
  o.z = p0*(bf2f(a.z) + z0.z) + p1*(bf2f(b.z) + z1.z);
  o.w = p0*(bf2f(a.w) + z0.w) + p1*(bf2f(b.w) + z1.w);
  *(f32x4*)(out + (size_t)t * D_DIM + 4*lane) = o;
}

extern "C" void kernel_launch(void* const* d_in, const int* in_sizes, int n_in,
                              void* d_out, int out_size, void* d_ws, size_t ws_size,
                              hipStream_t stream) {
  const float* x  = (const float*)d_in[0];
  const float* Wg = (const float*)d_in[1];
  const float* bg = (const float*)d_in[2];
  const float* W1 = (const float*)d_in[3];
  const float* b1 = (const float*)d_in[4];
  const float* W2 = (const float*)d_in[5];
  const float* b2 = (const float*)d_in[6];
  float* out = (float*)d_out;
  char* ws = (char*)d_ws;

  char*  wsw     = ws;                        // 8,388,608 B swizzled weights
  int*   counts  = (int*)  (ws + 8388608);    // 512 B (8 x 64B lines)
  int*   tok_ids = (int*)  (ws + 8389632);    // 2,097,152 B
  float* rrec    = (float*)(ws + 10486784);   // 1,048,576 B (f32x4 per token)

  hipMemsetAsync(counts, 0, 512, stream);
  gate_kernel<<<T_TOKENS/GTB, 256, 0, stream>>>(x, Wg, bg, W1, W2, wsw,
                                                counts, tok_ids, rrec);
  ffn_kernel<<<E_NUM * (T_TOKENS/MT), 256, 0, stream>>>(x, wsw, b1, counts, tok_ids,
                                                        (unsigned short*)d_out);
  combine_kernel<<<T_TOKENS/4, 256, 0, stream>>>(rrec, b2, out);
}